// Round 22
// baseline (169.174 us; speedup 1.0000x reference)
//
#include <hip/hip_runtime.h>
#include <hip/hip_bf16.h>
#include <cstdint>
#include <cstddef>

typedef __bf16 bf16x8 __attribute__((ext_vector_type(8)));
typedef float f32x4 __attribute__((ext_vector_type(4)));

#define DI __device__ __forceinline__
#define AS1 __attribute__((address_space(1)))
#define AS3 __attribute__((address_space(3)))

DI unsigned short f2bf(float x) {
    union { float f; unsigned int u; } v; v.f = x;
    unsigned int u = v.u;
    u += 0x7FFFu + ((u >> 16) & 1u);
    return (unsigned short)(u >> 16);
}

#define BATCH 64
#define NH 12
#define NTOK 197
#define NTOK_P 208   // 13*16
#define HD 64
#define DIM 768
#define MROWS 12608  // BATCH*NTOK
#define MPAD 224     // padded kv length for PV (v^T global)
#define PL4 72       // attn P LDS row stride
#define CPAD 132     // gemm epilogue LDS row stride
#define QSCALE 0.18033688f  // 64^-0.5 * log2(e)
#define LOG2E 1.4426950408889634f

// bijective XCD-aware swizzle (m204)
DI int xcd_swz(int orig, int nwg) {
    int q = nwg >> 3, r = nwg & 7;
    int x = orig & 7, l = orig >> 3;
    return (x < r ? x * (q + 1) : r * (q + 1) + (x - r) * q) + l;
}

// packed LDS offset for a 128x32 bf16 tile stored as phys[64][64] with 8-slot
// XOR swizzle (R5/R8/R9 correctness-verified, SQ_LDS_BANK_CONFLICT = 0):
// logical (r,k), r in [0,128), k in [0,32): prow=r>>1, pcol=(r&1)*32+k, ^=(prow&7)*8
DI int pk(int r, int k) {
    int prow = r >> 1;
    int pcol = ((r & 1) << 5) + k;
    return prow * 64 + (pcol ^ ((prow & 7) << 3));
}

// ---------------- prep kernels ----------------

// fused bf16 conversion of x, qkv_w, proj_w (one launch)
__global__ void cvt3_bf16_kernel(const float* __restrict__ a, unsigned short* __restrict__ oa, int na4,
                                 const float* __restrict__ b, unsigned short* __restrict__ ob, int nb4,
                                 const float* __restrict__ c, unsigned short* __restrict__ oc, int nc4) {
    int i = blockIdx.x * blockDim.x + threadIdx.x;
    const float* src; unsigned short* dst; int k;
    if (i < na4) { src = a; dst = oa; k = i; }
    else if (i < na4 + nb4) { src = b; dst = ob; k = i - na4; }
    else if (i < na4 + nb4 + nc4) { src = c; dst = oc; k = i - na4 - nb4; }
    else return;
    float4 f = ((const float4*)src)[k];
    ushort4 o;
    o.x = f2bf(f.x); o.y = f2bf(f.y); o.z = f2bf(f.z); o.w = f2bf(f.w);
    ((ushort4*)dst)[k] = o;
}

// merged: (a) rpb relayout for 32-row q-tiles; (b) v^T pad-column zeroing.
#define NRPB (NH * 7 * 13 * 512)                    // 598016
#define NPAD (BATCH * NH * HD * (MPAD - NTOK))      // 1327104
__global__ void prep2_kernel(const float* __restrict__ table, const int* __restrict__ idx,
                             float* __restrict__ out, unsigned short* __restrict__ vt) {
    int i = blockIdx.x * blockDim.x + threadIdx.x;
    if (i < NRPB) {
        int j = i & 3;
        int g = (i >> 2) & 1;
        int lane = (i >> 3) & 63;
        int rest = i >> 9;              // (h*7+qt)*13 + t
        int t = rest % 13;
        int qt = (rest / 13) % 7;
        int h = rest / 91;
        int row = qt * 32 + g * 16 + ((lane >> 4) << 2) + j;
        int col = t * 16 + (lane & 15);
        float v = 0.f;
        if (row < NTOK && col < NTOK) v = table[idx[row * NTOK + col] * NH + h] * LOG2E;
        out[i] = v;
    } else if (i < NRPB + NPAD) {
        int k = i - NRPB;
        const int npad = MPAD - NTOK; // 27
        int c = NTOK + (k % npad);
        int row = k / npad;
        vt[(size_t)row * MPAD + c] = 0;
    }
}

// ---------------- NT GEMM: ring-3 BK=32, counted-vmcnt, 1 barrier/iter ----------------
// C[m,n] = sum_k A[m,k]*W[n,k], K=768, 24 K-tiles of 32. 48KB static LDS:
// A ring [3][64][64] @0, B ring [3][64][64] @12288 (shorts).
// Schedule per iter t (extends R19's verified T4 idiom):
//   stage(t+2 -> buf[(t+2)%3])   [target retired last iter; overlaps compute]
//   ds_read buf[t%3] (8x b128) -> 16 MFMA (setprio)
//   lgkmcnt(0)                   [own reads retired -> buf dead after barrier]
//   vmcnt(4)                     [tile t+1 (staged at t-1) landed; t+2 in flight]
//   s_barrier                    [single barrier per iteration]
// 3 blocks/CU (12 waves) vs R19's 2 (8). R9's BK=32 failure was pre-T4
// (vmcnt(0) drains); those are gone here.
// EPI 0: qkv epilogue; EPI 1: proj epilogue (both byte-identical to R19/R21).

template<int EPI>
__launch_bounds__(256)
__global__ void gemm_bt_kernel(const unsigned short* __restrict__ A,
                               const unsigned short* __restrict__ W,
                               const float* __restrict__ bias0,
                               const float* __restrict__ bias1,
                               void* __restrict__ out0,
                               unsigned short* __restrict__ out1,
                               unsigned short* __restrict__ out2,
                               int M, int ntiles)
{
    __shared__ __align__(16) unsigned short smem[24576]; // 48KB: A[3]@0 | B[3]@12288
    const int K = DIM;
    const int NT = 24; // K/32
    int wgid = xcd_swz(blockIdx.x, gridDim.x);
    int mt = wgid / ntiles, nt = wgid % ntiles;
    int m0 = mt * 128, n0 = nt * 128;
    int tid = threadIdx.x;
    int lane = tid & 63, w = tid >> 6;
    int wr = (w >> 1) * 64, wc = (w & 1) * 64;
    int r15 = lane & 15, hi8 = (lane >> 4) * 8;

    f32x4 acc[4][4] = {};

    // stage one BK=32 tile pair into ring buffer `buf` (A 8KB + B 8KB);
    // 4 global_load_lds/thread, linear dest, source = inverse pk() (R5-verified).
    auto stage = [&](int buf, int ks) {
        unsigned short* as = smem + buf * 4096;
        unsigned short* bs = smem + 12288 + buf * 4096;
#pragma unroll
        for (int r0 = 0; r0 < 2; ++r0) {
            int L = r0 * 256 + tid;
            int prow = L >> 3, ls = (L & 7) ^ (prow & 7);
            int rr = (prow << 1) + (ls >> 2), kk = (ls & 3) << 3;
            int arow = m0 + rr; if (arow >= M) arow = M - 1;
            __builtin_amdgcn_global_load_lds(
                (const AS1 void*)(A + (size_t)arow * K + ks + kk),
                (AS3 void*)(as + r0 * 2048 + w * 512), 16, 0, 0);
            __builtin_amdgcn_global_load_lds(
                (const AS1 void*)(W + (size_t)(n0 + rr) * K + ks + kk),
                (AS3 void*)(bs + r0 * 2048 + w * 512), 16, 0, 0);
        }
    };

    // prologue: tiles 0,1 staged (8 loads); vmcnt(4) -> tile0 landed, tile1 in flight
    stage(0, 0);
    stage(1, 32);
    asm volatile("s_waitcnt vmcnt(4)" ::: "memory");
    __builtin_amdgcn_sched_barrier(0);
    __builtin_amdgcn_s_barrier();

    for (int t = 0; t < NT; ++t) {
        int cb = t % 3;
        if (t + 2 < NT) stage((t + 2) % 3, (t + 2) * 32); // target = buf computed at t-1, retired
        __builtin_amdgcn_sched_barrier(0); // keep stage issue ahead of reads/MFMA
        const unsigned short* as = smem + cb * 4096;
        const unsigned short* bs = smem + 12288 + cb * 4096;
        bf16x8 af[4], bfr[4];
#pragma unroll
        for (int x = 0; x < 4; x++)
            af[x] = *(const bf16x8*)&as[pk(wr + x * 16 + r15, hi8)];
#pragma unroll
        for (int y = 0; y < 4; y++)
            bfr[y] = *(const bf16x8*)&bs[pk(wc + y * 16 + r15, hi8)];
        __builtin_amdgcn_s_setprio(1);
#pragma unroll
        for (int x = 0; x < 4; x++)
#pragma unroll
            for (int y = 0; y < 4; y++)
                acc[x][y] = __builtin_amdgcn_mfma_f32_16x16x32_bf16(af[x], bfr[y], acc[x][y], 0, 0, 0);
        __builtin_amdgcn_s_setprio(0);
        // own reads of buf[cb] retired -> after barrier, next iter may overwrite it
        asm volatile("s_waitcnt lgkmcnt(0)" ::: "memory");
        __builtin_amdgcn_sched_barrier(0);
        if (t + 2 < NT) {
            // tile t+1 (staged at iter t-1) landed; tile t+2's 4 loads stay in flight
            asm volatile("s_waitcnt vmcnt(4)" ::: "memory");
        } else {
            asm volatile("s_waitcnt vmcnt(0)" ::: "memory");
        }
        __builtin_amdgcn_sched_barrier(0);
        __builtin_amdgcn_s_barrier();
    }

    if constexpr (EPI == 1) {
        // proj: fp32 direct stores (64B segments)
#pragma unroll
        for (int x = 0; x < 4; x++)
#pragma unroll
            for (int y = 0; y < 4; y++)
#pragma unroll
                for (int j = 0; j < 4; j++) {
                    int m = m0 + wr + x * 16 + (lane >> 4) * 4 + j;
                    int n = n0 + wc + y * 16 + r15;
                    if (m < M)
                        ((float*)out0)[(size_t)m * DIM + n] = acc[x][y][j] + bias0[n];
                }
    } else {
        // qkv: one 128-tile lies entirely within q, k, or v (768 = 6*128)
        int which = n0 / DIM;
        int hn0 = n0 - which * DIM; // multiple of 128 -> tile covers 2 heads
        unsigned short* lc = smem;  // [128][CPAD] bf16, 33.8 KB

        __syncthreads();
#pragma unroll
        for (int x = 0; x < 4; x++)
#pragma unroll
            for (int y = 0; y < 4; y++)
#pragma unroll
                for (int j = 0; j < 4; j++) {
                    int ml = wr + x * 16 + (lane >> 4) * 4 + j;
                    int nl = wc + y * 16 + r15;
                    float val = acc[x][y][j];
                    if (which == 0) val = (val + bias0[hn0 + nl]) * QSCALE;
                    else if (which == 2) val = val + bias1[hn0 + nl];
                    lc[ml * CPAD + nl] = f2bf(val);
                }
        __syncthreads();

        if (which != 2) {
            // q/k: [BH,208,64]; per wave-instr: 4x 128B coalesced segments
            unsigned short* outq = (which == 0) ? (unsigned short*)out0 : out1;
            int c4 = (lane & 31) * 4;
            int h = (hn0 >> 6) + (c4 >> 6), d = c4 & 63;
            for (int it = 0; it < 16; ++it) {
                int r = it * 8 + w * 2 + (lane >> 5);
                int m = m0 + r;
                if (m >= M) continue;
                int b = m / NTOK, t = m - b * NTOK;
                ushort4 q4 = *(const ushort4*)&lc[r * CPAD + c4];
                *(ushort4*)&outq[(((size_t)b * NH + h) * NTOK_P + t) * HD + d] = q4;
            }
        } else {
            // v^T: [BH,64,224]; lanes are consecutive t -> coalesced along rows
            int mh = w >> 1, hs = w & 1;
            int h = (hn0 >> 6) + hs;
            int ml = mh * 64 + lane;
            int m = m0 + ml;
            if (m < M) {
                int b = m / NTOK, t = m - b * NTOK;
                unsigned short* vbase = out2 + (((size_t)b * NH + h) * HD) * MPAD + t;
#pragma unroll 8
                for (int d = 0; d < 64; ++d)
                    vbase[(size_t)d * MPAD] = lc[ml * CPAD + hs * 64 + d];
            }
        }
    }
}

// ---------------- fused attention — 32 q-rows/wave, split-KV-4 (R21-verified best) ----------------

__launch_bounds__(64)
__global__ void attn_kernel(const unsigned short* __restrict__ qbuf, // [BH,208,64]
                            const unsigned short* __restrict__ kbuf, // [BH,208,64]
                            const unsigned short* __restrict__ vt,   // [BH,64,224]
                            const float* __restrict__ rpb2,          // [12][7][13][64][8] coalesced
                            unsigned short* __restrict__ ao)         // [12608,768]
{
    __shared__ __align__(16) unsigned short p_lds[32][PL4];
    int bid = xcd_swz(blockIdx.x, gridDim.x);
    int qt = bid % 7, bh = bid / 7;
    int b = bh / NH, h = bh - b * NH;
    int lane = threadIdx.x;
    int r0 = qt * 32;
    int col_l = lane & 15, hi = lane >> 4;

    const size_t kqbase = (size_t)bh * NTOK_P * HD;
    int qr0 = r0 + col_l;      if (qr0 > NTOK_P - 1) qr0 = NTOK_P - 1;
    int qr1 = r0 + 16 + col_l; if (qr1 > NTOK_P - 1) qr1 = NTOK_P - 1;
    bf16x8 qf0a = *(const bf16x8*)&qbuf[kqbase + (size_t)qr0 * HD + hi * 8];
    bf16x8 qf0b = *(const bf16x8*)&qbuf[kqbase + (size_t)qr0 * HD + 32 + hi * 8];
    bf16x8 qf1a = *(const bf16x8*)&qbuf[kqbase + (size_t)qr1 * HD + hi * 8];
    bf16x8 qf1b = *(const bf16x8*)&qbuf[kqbase + (size_t)qr1 * HD + 32 + hi * 8];

    const float* rpbase = rpb2 + ((size_t)(h * 7 + qt) * 13) * 512 + lane * 8;
    const size_t vbase = (size_t)bh * HD * MPAD;

    float lrow[2][4] = {};
    f32x4 o[2][4] = {};

#pragma unroll
    for (int ch = 0; ch < 4; ++ch) {
        const int t0 = ch * 4;
        const int t1 = (ch == 3) ? 13 : (t0 + 4);
#pragma unroll
        for (int t = t0; t < t1; t++) {
            int krow = t * 16 + col_l;
            bf16x8 kf0 = *(const bf16x8*)&kbuf[kqbase + (size_t)krow * HD + hi * 8];
            bf16x8 kf1 = *(const bf16x8*)&kbuf[kqbase + (size_t)krow * HD + 32 + hi * 8];
            f32x4 z = {0.f, 0.f, 0.f, 0.f};
            f32x4 sA = __builtin_amdgcn_mfma_f32_16x16x32_bf16(qf0a, kf0, z, 0, 0, 0);
            sA = __builtin_amdgcn_mfma_f32_16x16x32_bf16(qf0b, kf1, sA, 0, 0, 0);
            f32x4 sB = __builtin_amdgcn_mfma_f32_16x16x32_bf16(qf1a, kf0, z, 0, 0, 0);
            sB = __builtin_amdgcn_mfma_f32_16x16x32_bf16(qf1b, kf1, sB, 0, 0, 0);
            float4 ra = *(const float4*)&rpbase[(size_t)t * 512];
            float4 rb = *(const float4*)&rpbase[(size_t)t * 512 + 4];
            float raj[4] = {ra.x, ra.y, ra.z, ra.w};
            float rbj[4] = {rb.x, rb.y, rb.z, rb.w};
            bool masked = (t * 16 + col_l >= NTOK);
            int pc = (t - t0) * 16 + col_l;
#pragma unroll
            for (int j = 0; j < 4; j++) {
                float vA = sA[j] + raj[j];
                float vB = sB[j] + rbj[j];
                if (masked) { vA = -1e30f; vB = -1e30f; }
                float pA = exp2f(vA);
                float pB = exp2f(vB);
                lrow[0][j] += pA;
                lrow[1][j] += pB;
                p_lds[hi * 4 + j][pc] = f2bf(pA);
                p_lds[16 + hi * 4 + j][pc] = f2bf(pB);
            }
        }
        if (ch == 3) {
            ushort4 z4 = {0, 0, 0, 0};
            *(ushort4*)&p_lds[col_l][16 + hi * 4] = z4;
            *(ushort4*)&p_lds[16 + col_l][16 + hi * 4] = z4;
        }
        const int c0 = ch * 2;
        const int c1 = (ch == 3) ? 7 : (c0 + 2);
        __builtin_amdgcn_s_setprio(1);
#pragma unroll
        for (int c = c0; c < c1; c++) {
            int bcol = (c - c0) * 32;
            bf16x8 pf0 = *(const bf16x8*)&p_lds[col_l][bcol + hi * 8];
            bf16x8 pf1 = *(const bf16x8*)&p_lds[16 + col_l][bcol + hi * 8];
#pragma unroll
            for (int n = 0; n < 4; n++) {
                bf16x8 vf = *(const bf16x8*)&vt[vbase + (size_t)(n * 16 + col_l) * MPAD + c * 32 + hi * 8];
                o[0][n] = __builtin_amdgcn_mfma_f32_16x16x32_bf16(pf0, vf, o[0][n], 0, 0, 0);
                o[1][n] = __builtin_amdgcn_mfma_f32_16x16x32_bf16(pf1, vf, o[1][n], 0, 0, 0);
            }
        }
        __builtin_amdgcn_s_setprio(0);
    }

    float inv[2][4];
#pragma unroll
    for (int g = 0; g < 2; g++)
#pragma unroll
        for (int j = 0; j < 4; j++) {
            float lv = lrow[g][j];
            lv += __shfl_xor(lv, 1);
            lv += __shfl_xor(lv, 2);
            lv += __shfl_xor(lv, 4);
            lv += __shfl_xor(lv, 8);
            inv[g][j] = __builtin_amdgcn_rcpf(lv);
        }

#pragma unroll
    for (int g = 0; g < 2; g++)
#pragma unroll
        for (int n = 0; n < 4; n++)
#pragma unroll
            for (int j = 0; j < 4; j++) {
                int tok = r0 + g * 16 + hi * 4 + j;
                if (tok < NTOK) {
                    float val = o[g][n][j] * inv[g][j];
                    ao[((size_t)b * NTOK + tok) * DIM + h * HD + n * 16 + col_l] = f2bf(val);
                }
            }
}

// ---------------- launcher ----------------

extern "C" void kernel_launch(void* const* d_in, const int* in_sizes, int n_in,
                              void* d_out, int out_size, void* d_ws, size_t ws_size,
                              hipStream_t stream)
{
    const float* x      = (const float*)d_in[0];
    const float* qkv_w  = (const float*)d_in[1];
    const float* q_bias = (const float*)d_in[2];
    const float* v_bias = (const float*)d_in[3];
    const float* rpb_t  = (const float*)d_in[4];
    const float* proj_w = (const float*)d_in[5];
    const float* proj_b = (const float*)d_in[6];
    const int*   relidx = (const int*)d_in[7];
    float* out = (float*)d_out;

    char* ws = (char*)d_ws;
    const size_t SZ_XBF  = (size_t)MROWS * DIM * 2;              // also reused as attn-out
    const size_t SZ_QKVW = (size_t)3 * DIM * DIM * 2;
    const size_t SZ_PRJW = (size_t)DIM * DIM * 2;
    const size_t SZ_QK   = (size_t)BATCH * NH * NTOK_P * HD * 2;
    const size_t SZ_VT   = (size_t)BATCH * NH * HD * MPAD * 2;

    unsigned short* x_bf = (unsigned short*)ws;
    unsigned short* ao   = x_bf; // aliased: x_bf dead after QKV gemm
    size_t off = SZ_XBF;
    unsigned short* qkvw_bf  = (unsigned short*)(ws + off); off += SZ_QKVW;
    unsigned short* projw_bf = (unsigned short*)(ws + off); off += SZ_PRJW;
    unsigned short* qbuf     = (unsigned short*)(ws + off); off += SZ_QK;
    unsigned short* kbuf     = (unsigned short*)(ws + off); off += SZ_QK;
    unsigned short* vtbuf    = (unsigned short*)(ws + off); off += SZ_VT;
    float* rpbf              = (float*)(ws + off);

    // prep (2 launches)
    const int NA4 = MROWS * DIM / 4, NB4 = 3 * DIM * DIM / 4, NC4 = DIM * DIM / 4;
    cvt3_bf16_kernel<<<(NA4 + NB4 + NC4 + 255) / 256, 256, 0, stream>>>(
        x, x_bf, NA4, qkv_w, qkvw_bf, NB4, proj_w, projw_bf, NC4);
    prep2_kernel<<<(NRPB + NPAD + 255) / 256, 256, 0, stream>>>(rpb_t, relidx, rpbf, vtbuf);

    // QKV gemm: M=12608, N=2304 (18 n-tiles of 128), fused bias/scale + retile
    gemm_bt_kernel<0><<<99 * 18, 256, 0, stream>>>(x_bf, qkvw_bf, q_bias, v_bias,
                                                   (void*)qbuf, kbuf, vtbuf, MROWS, 18);
    // fused attention: one wave per 32 q-rows, split-KV-4
    attn_kernel<<<BATCH * NH * 7, 64, 0, stream>>>(qbuf, kbuf, vtbuf, rpbf, ao);
    // proj gemm: M=12608, N=768 (6 n-tiles of 128), fp32 out + bias
    gemm_bt_kernel<1><<<99 * 6, 256, 0, stream>>>(ao, projw_bf, proj_b, nullptr,
                                                  (void*)out, nullptr, nullptr, MROWS, 6);
    (void)in_sizes; (void)n_in; (void)out_size; (void)ws_size;
}

// Round 23
// 166.258 us; speedup vs baseline: 1.0175x; 1.0175x over previous
//
#include <hip/hip_runtime.h>
#include <hip/hip_bf16.h>
#include <cstdint>
#include <cstddef>

typedef __bf16 bf16x8 __attribute__((ext_vector_type(8)));
typedef float f32x4 __attribute__((ext_vector_type(4)));

#define DI __device__ __forceinline__
#define AS1 __attribute__((address_space(1)))
#define AS3 __attribute__((address_space(3)))

DI unsigned short f2bf(float x) {
    union { float f; unsigned int u; } v; v.f = x;
    unsigned int u = v.u;
    u += 0x7FFFu + ((u >> 16) & 1u);
    return (unsigned short)(u >> 16);
}

#define BATCH 64
#define NH 12
#define NTOK 197
#define NTOK_P 208   // 13*16
#define HD 64
#define DIM 768
#define MROWS 12608  // BATCH*NTOK
#define MPAD 224     // padded kv length for PV (v^T global)
#define PL4 72       // attn P LDS row stride
#define CPAD 132     // gemm epilogue LDS row stride
#define QSCALE 0.18033688f  // 64^-0.5 * log2(e)
#define LOG2E 1.4426950408889634f

// bijective XCD-aware swizzle (m204)
DI int xcd_swz(int orig, int nwg) {
    int q = nwg >> 3, r = nwg & 7;
    int x = orig & 7, l = orig >> 3;
    return (x < r ? x * (q + 1) : r * (q + 1) + (x - r) * q) + l;
}

// LDS XOR swizzle for [*][64] bf16 tiles (elems) — R3/R7-verified, 0 conflicts
DI int swz(int row, int col_elem) {
    return (row * 64 + col_elem) ^ ((row & 7) << 3);
}

// packed LDS offset for a 128x32 bf16 tile in phys[64][64] with 8-slot XOR
// swizzle (R5/R8/R9/R22-verified, 0 conflicts)
DI int pk(int r, int k) {
    int prow = r >> 1;
    int pcol = ((r & 1) << 5) + k;
    return prow * 64 + (pcol ^ ((prow & 7) << 3));
}

// ---------------- prep kernels ----------------

// fused bf16 conversion of x, qkv_w, proj_w (one launch)
__global__ void cvt3_bf16_kernel(const float* __restrict__ a, unsigned short* __restrict__ oa, int na4,
                                 const float* __restrict__ b, unsigned short* __restrict__ ob, int nb4,
                                 const float* __restrict__ c, unsigned short* __restrict__ oc, int nc4) {
    int i = blockIdx.x * blockDim.x + threadIdx.x;
    const float* src; unsigned short* dst; int k;
    if (i < na4) { src = a; dst = oa; k = i; }
    else if (i < na4 + nb4) { src = b; dst = ob; k = i - na4; }
    else if (i < na4 + nb4 + nc4) { src = c; dst = oc; k = i - na4 - nb4; }
    else return;
    float4 f = ((const float4*)src)[k];
    ushort4 o;
    o.x = f2bf(f.x); o.y = f2bf(f.y); o.z = f2bf(f.z); o.w = f2bf(f.w);
    ((ushort4*)dst)[k] = o;
}

// merged: (a) rpb relayout for 32-row q-tiles; (b) v^T pad-column zeroing.
#define NRPB (NH * 7 * 13 * 512)                    // 598016
#define NPAD (BATCH * NH * HD * (MPAD - NTOK))      // 1327104
__global__ void prep2_kernel(const float* __restrict__ table, const int* __restrict__ idx,
                             float* __restrict__ out, unsigned short* __restrict__ vt) {
    int i = blockIdx.x * blockDim.x + threadIdx.x;
    if (i < NRPB) {
        int j = i & 3;
        int g = (i >> 2) & 1;
        int lane = (i >> 3) & 63;
        int rest = i >> 9;              // (h*7+qt)*13 + t
        int t = rest % 13;
        int qt = (rest / 13) % 7;
        int h = rest / 91;
        int row = qt * 32 + g * 16 + ((lane >> 4) << 2) + j;
        int col = t * 16 + (lane & 15);
        float v = 0.f;
        if (row < NTOK && col < NTOK) v = table[idx[row * NTOK + col] * NH + h] * LOG2E;
        out[i] = v;
    } else if (i < NRPB + NPAD) {
        int k = i - NRPB;
        const int npad = MPAD - NTOK; // 27
        int c = NTOK + (k % npad);
        int row = k / npad;
        vt[(size_t)row * MPAD + c] = 0;
    }
}

// ---------------- QKV GEMM: R19-verified (2-phase BK=64, T4 counted-vmcnt) ----------------
// C[m,n] = sum_k A[m,k]*W[n,k], K=768. 128x128 tile. Measured 79.7 µs (565 TF).
// Schedule: compute(buf) -> lgkmcnt(0)+barrier -> stage(buf, t+2) -> vmcnt(8) -> barrier.

__launch_bounds__(256)
__global__ void qkv_gemm_kernel(const unsigned short* __restrict__ A,
                                const unsigned short* __restrict__ W,
                                const float* __restrict__ bias0,
                                const float* __restrict__ bias1,
                                unsigned short* __restrict__ out0,
                                unsigned short* __restrict__ out1,
                                unsigned short* __restrict__ out2,
                                int M, int ntiles)
{
    __shared__ __align__(16) unsigned short smem[32768]; // 64 KB
    const int K = DIM;
    const int NT = K / 64; // 12
    int wgid = xcd_swz(blockIdx.x, gridDim.x);
    int mt = wgid / ntiles, nt = wgid % ntiles;
    int m0 = mt * 128, n0 = nt * 128;
    int tid = threadIdx.x;
    int lane = tid & 63, w = tid >> 6;
    int wr = (w >> 1) * 64, wc = (w & 1) * 64;

    const int st_row = lane >> 3;
    const int st_col = ((lane & 7) ^ (lane >> 3)) << 3;

    f32x4 acc[4][4] = {};

    auto stage = [&](int buf, int ks) {
        unsigned short* as = smem + buf * 8192;
        unsigned short* bs = smem + 16384 + buf * 8192;
#pragma unroll
        for (int i = 0; i < 4; i++) {
            int s = w * 4 + i;
            int arow = m0 + s * 8 + st_row; if (arow >= M) arow = M - 1;
            __builtin_amdgcn_global_load_lds(
                (const AS1 void*)(A + (size_t)arow * K + ks + st_col),
                (AS3 void*)(as + s * 512), 16, 0, 0);
        }
#pragma unroll
        for (int i = 0; i < 4; i++) {
            int s = w * 4 + i;
            __builtin_amdgcn_global_load_lds(
                (const AS1 void*)(W + (size_t)(n0 + s * 8 + st_row) * K + ks + st_col),
                (AS3 void*)(bs + s * 512), 16, 0, 0);
        }
    };

    stage(0, 0);
    stage(1, 64);
    asm volatile("s_waitcnt vmcnt(8)" ::: "memory");
    __builtin_amdgcn_sched_barrier(0);
    __builtin_amdgcn_s_barrier();

    for (int t = 0; t < NT; ++t) {
        int buf = t & 1;
        const unsigned short* as = smem + buf * 8192;
        const unsigned short* bs = smem + 16384 + buf * 8192;
#pragma unroll
        for (int kc = 0; kc < 2; kc++) {
            bf16x8 af[4], bfr[4];
#pragma unroll
            for (int x = 0; x < 4; x++)
                af[x] = *(const bf16x8*)&as[swz(wr + x * 16 + (lane & 15), kc * 32 + (lane >> 4) * 8)];
#pragma unroll
            for (int y = 0; y < 4; y++)
                bfr[y] = *(const bf16x8*)&bs[swz(wc + y * 16 + (lane & 15), kc * 32 + (lane >> 4) * 8)];
            __builtin_amdgcn_s_setprio(1);
#pragma unroll
            for (int x = 0; x < 4; x++)
#pragma unroll
                for (int y = 0; y < 4; y++)
                    acc[x][y] = __builtin_amdgcn_mfma_f32_16x16x32_bf16(af[x], bfr[y], acc[x][y], 0, 0, 0);
            __builtin_amdgcn_s_setprio(0);
        }
        asm volatile("s_waitcnt lgkmcnt(0)" ::: "memory");
        __builtin_amdgcn_sched_barrier(0);
        __builtin_amdgcn_s_barrier();
        if (t + 2 < NT) {
            stage(buf, (t + 2) * 64);
            asm volatile("s_waitcnt vmcnt(8)" ::: "memory");
        } else {
            asm volatile("s_waitcnt vmcnt(0)" ::: "memory");
        }
        __builtin_amdgcn_sched_barrier(0);
        __builtin_amdgcn_s_barrier();
    }

    // qkv epilogue (R19-verified)
    int which = n0 / DIM;
    int hn0 = n0 - which * DIM;
    unsigned short* lc = smem;

    __syncthreads();
#pragma unroll
    for (int x = 0; x < 4; x++)
#pragma unroll
        for (int y = 0; y < 4; y++)
#pragma unroll
            for (int j = 0; j < 4; j++) {
                int ml = wr + x * 16 + (lane >> 4) * 4 + j;
                int nl = wc + y * 16 + (lane & 15);
                float val = acc[x][y][j];
                if (which == 0) val = (val + bias0[hn0 + nl]) * QSCALE;
                else if (which == 2) val = val + bias1[hn0 + nl];
                lc[ml * CPAD + nl] = f2bf(val);
            }
    __syncthreads();

    if (which != 2) {
        unsigned short* outq = (which == 0) ? out0 : out1;
        int c4 = (lane & 31) * 4;
        int h = (hn0 >> 6) + (c4 >> 6), d = c4 & 63;
        for (int it = 0; it < 16; ++it) {
            int r = it * 8 + w * 2 + (lane >> 5);
            int m = m0 + r;
            if (m >= M) continue;
            int b = m / NTOK, t = m - b * NTOK;
            ushort4 q4 = *(const ushort4*)&lc[r * CPAD + c4];
            *(ushort4*)&outq[(((size_t)b * NH + h) * NTOK_P + t) * HD + d] = q4;
        }
    } else {
        int mh = w >> 1, hs = w & 1;
        int h = (hn0 >> 6) + hs;
        int ml = mh * 64 + lane;
        int m = m0 + ml;
        if (m < M) {
            int b = m / NTOK, t = m - b * NTOK;
            unsigned short* vbase = out2 + (((size_t)b * NH + h) * HD) * MPAD + t;
#pragma unroll 8
            for (int d = 0; d < 64; ++d)
                vbase[(size_t)d * MPAD] = lc[ml * CPAD + hs * 64 + d];
        }
    }
}

// ---------------- proj GEMM: R22-verified ring-3 BK=32 (3 blocks/CU -> 594 blocks in ONE round) ----------------

__launch_bounds__(256)
__global__ void proj_gemm_kernel(const unsigned short* __restrict__ A,
                                 const unsigned short* __restrict__ W,
                                 const float* __restrict__ bias,
                                 float* __restrict__ out, int M, int ntiles)
{
    __shared__ __align__(16) unsigned short smem[24576]; // 48KB: A[3]@0 | B[3]@12288
    const int K = DIM;
    const int NT = 24; // K/32
    int wgid = xcd_swz(blockIdx.x, gridDim.x);
    int mt = wgid / ntiles, nt = wgid % ntiles;
    int m0 = mt * 128, n0 = nt * 128;
    int tid = threadIdx.x;
    int lane = tid & 63, w = tid >> 6;
    int wr = (w >> 1) * 64, wc = (w & 1) * 64;
    int r15 = lane & 15, hi8 = (lane >> 4) * 8;

    f32x4 acc[4][4] = {};

    auto stage = [&](int buf, int ks) {
        unsigned short* as = smem + buf * 4096;
        unsigned short* bs = smem + 12288 + buf * 4096;
#pragma unroll
        for (int r0 = 0; r0 < 2; ++r0) {
            int L = r0 * 256 + tid;
            int prow = L >> 3, ls = (L & 7) ^ (prow & 7);
            int rr = (prow << 1) + (ls >> 2), kk = (ls & 3) << 3;
            int arow = m0 + rr; if (arow >= M) arow = M - 1;
            __builtin_amdgcn_global_load_lds(
                (const AS1 void*)(A + (size_t)arow * K + ks + kk),
                (AS3 void*)(as + r0 * 2048 + w * 512), 16, 0, 0);
            __builtin_amdgcn_global_load_lds(
                (const AS1 void*)(W + (size_t)(n0 + rr) * K + ks + kk),
                (AS3 void*)(bs + r0 * 2048 + w * 512), 16, 0, 0);
        }
    };

    stage(0, 0);
    stage(1, 32);
    asm volatile("s_waitcnt vmcnt(4)" ::: "memory");
    __builtin_amdgcn_sched_barrier(0);
    __builtin_amdgcn_s_barrier();

    for (int t = 0; t < NT; ++t) {
        int cb = t % 3;
        if (t + 2 < NT) stage((t + 2) % 3, (t + 2) * 32);
        __builtin_amdgcn_sched_barrier(0);
        const unsigned short* as = smem + cb * 4096;
        const unsigned short* bs = smem + 12288 + cb * 4096;
        bf16x8 af[4], bfr[4];
#pragma unroll
        for (int x = 0; x < 4; x++)
            af[x] = *(const bf16x8*)&as[pk(wr + x * 16 + r15, hi8)];
#pragma unroll
        for (int y = 0; y < 4; y++)
            bfr[y] = *(const bf16x8*)&bs[pk(wc + y * 16 + r15, hi8)];
        __builtin_amdgcn_s_setprio(1);
#pragma unroll
        for (int x = 0; x < 4; x++)
#pragma unroll
            for (int y = 0; y < 4; y++)
                acc[x][y] = __builtin_amdgcn_mfma_f32_16x16x32_bf16(af[x], bfr[y], acc[x][y], 0, 0, 0);
        __builtin_amdgcn_s_setprio(0);
        asm volatile("s_waitcnt lgkmcnt(0)" ::: "memory");
        __builtin_amdgcn_sched_barrier(0);
        if (t + 2 < NT) {
            asm volatile("s_waitcnt vmcnt(4)" ::: "memory");
        } else {
            asm volatile("s_waitcnt vmcnt(0)" ::: "memory");
        }
        __builtin_amdgcn_sched_barrier(0);
        __builtin_amdgcn_s_barrier();
    }

    // proj epilogue: fp32 direct stores + bias
#pragma unroll
    for (int x = 0; x < 4; x++)
#pragma unroll
        for (int y = 0; y < 4; y++)
#pragma unroll
            for (int j = 0; j < 4; j++) {
                int m = m0 + wr + x * 16 + (lane >> 4) * 4 + j;
                int n = n0 + wc + y * 16 + r15;
                if (m < M)
                    out[(size_t)m * DIM + n] = acc[x][y][j] + bias[n];
            }
}

// ---------------- fused attention — 32 q-rows/wave, split-KV-4 (R21-verified best) ----------------

__launch_bounds__(64)
__global__ void attn_kernel(const unsigned short* __restrict__ qbuf, // [BH,208,64]
                            const unsigned short* __restrict__ kbuf, // [BH,208,64]
                            const unsigned short* __restrict__ vt,   // [BH,64,224]
                            const float* __restrict__ rpb2,          // [12][7][13][64][8] coalesced
                            unsigned short* __restrict__ ao)         // [12608,768]
{
    __shared__ __align__(16) unsigned short p_lds[32][PL4];
    int bid = xcd_swz(blockIdx.x, gridDim.x);
    int qt = bid % 7, bh = bid / 7;
    int b = bh / NH, h = bh - b * NH;
    int lane = threadIdx.x;
    int r0 = qt * 32;
    int col_l = lane & 15, hi = lane >> 4;

    const size_t kqbase = (size_t)bh * NTOK_P * HD;
    int qr0 = r0 + col_l;      if (qr0 > NTOK_P - 1) qr0 = NTOK_P - 1;
    int qr1 = r0 + 16 + col_l; if (qr1 > NTOK_P - 1) qr1 = NTOK_P - 1;
    bf16x8 qf0a = *(const bf16x8*)&qbuf[kqbase + (size_t)qr0 * HD + hi * 8];
    bf16x8 qf0b = *(const bf16x8*)&qbuf[kqbase + (size_t)qr0 * HD + 32 + hi * 8];
    bf16x8 qf1a = *(const bf16x8*)&qbuf[kqbase + (size_t)qr1 * HD + hi * 8];
    bf16x8 qf1b = *(const bf16x8*)&qbuf[kqbase + (size_t)qr1 * HD + 32 + hi * 8];

    const float* rpbase = rpb2 + ((size_t)(h * 7 + qt) * 13) * 512 + lane * 8;
    const size_t vbase = (size_t)bh * HD * MPAD;

    float lrow[2][4] = {};
    f32x4 o[2][4] = {};

#pragma unroll
    for (int ch = 0; ch < 4; ++ch) {
        const int t0 = ch * 4;
        const int t1 = (ch == 3) ? 13 : (t0 + 4);
#pragma unroll
        for (int t = t0; t < t1; t++) {
            int krow = t * 16 + col_l;
            bf16x8 kf0 = *(const bf16x8*)&kbuf[kqbase + (size_t)krow * HD + hi * 8];
            bf16x8 kf1 = *(const bf16x8*)&kbuf[kqbase + (size_t)krow * HD + 32 + hi * 8];
            f32x4 z = {0.f, 0.f, 0.f, 0.f};
            f32x4 sA = __builtin_amdgcn_mfma_f32_16x16x32_bf16(qf0a, kf0, z, 0, 0, 0);
            sA = __builtin_amdgcn_mfma_f32_16x16x32_bf16(qf0b, kf1, sA, 0, 0, 0);
            f32x4 sB = __builtin_amdgcn_mfma_f32_16x16x32_bf16(qf1a, kf0, z, 0, 0, 0);
            sB = __builtin_amdgcn_mfma_f32_16x16x32_bf16(qf1b, kf1, sB, 0, 0, 0);
            float4 ra = *(const float4*)&rpbase[(size_t)t * 512];
            float4 rb = *(const float4*)&rpbase[(size_t)t * 512 + 4];
            float raj[4] = {ra.x, ra.y, ra.z, ra.w};
            float rbj[4] = {rb.x, rb.y, rb.z, rb.w};
            bool masked = (t * 16 + col_l >= NTOK);
            int pc = (t - t0) * 16 + col_l;
#pragma unroll
            for (int j = 0; j < 4; j++) {
                float vA = sA[j] + raj[j];
                float vB = sB[j] + rbj[j];
                if (masked) { vA = -1e30f; vB = -1e30f; }
                float pA = exp2f(vA);
                float pB = exp2f(vB);
                lrow[0][j] += pA;
                lrow[1][j] += pB;
                p_lds[hi * 4 + j][pc] = f2bf(pA);
                p_lds[16 + hi * 4 + j][pc] = f2bf(pB);
            }
        }
        if (ch == 3) {
            ushort4 z4 = {0, 0, 0, 0};
            *(ushort4*)&p_lds[col_l][16 + hi * 4] = z4;
            *(ushort4*)&p_lds[16 + col_l][16 + hi * 4] = z4;
        }
        const int c0 = ch * 2;
        const int c1 = (ch == 3) ? 7 : (c0 + 2);
        __builtin_amdgcn_s_setprio(1);
#pragma unroll
        for (int c = c0; c < c1; c++) {
            int bcol = (c - c0) * 32;
            bf16x8 pf0 = *(const bf16x8*)&p_lds[col_l][bcol + hi * 8];
            bf16x8 pf1 = *(const bf16x8*)&p_lds[16 + col_l][bcol + hi * 8];
#pragma unroll
            for (int n = 0; n < 4; n++) {
                bf16x8 vf = *(const bf16x8*)&vt[vbase + (size_t)(n * 16 + col_l) * MPAD + c * 32 + hi * 8];
                o[0][n] = __builtin_amdgcn_mfma_f32_16x16x32_bf16(pf0, vf, o[0][n], 0, 0, 0);
                o[1][n] = __builtin_amdgcn_mfma_f32_16x16x32_bf16(pf1, vf, o[1][n], 0, 0, 0);
            }
        }
        __builtin_amdgcn_s_setprio(0);
    }

    float inv[2][4];
#pragma unroll
    for (int g = 0; g < 2; g++)
#pragma unroll
        for (int j = 0; j < 4; j++) {
            float lv = lrow[g][j];
            lv += __shfl_xor(lv, 1);
            lv += __shfl_xor(lv, 2);
            lv += __shfl_xor(lv, 4);
            lv += __shfl_xor(lv, 8);
            inv[g][j] = __builtin_amdgcn_rcpf(lv);
        }

#pragma unroll
    for (int g = 0; g < 2; g++)
#pragma unroll
        for (int n = 0; n < 4; n++)
#pragma unroll
            for (int j = 0; j < 4; j++) {
                int tok = r0 + g * 16 + hi * 4 + j;
                if (tok < NTOK) {
                    float val = o[g][n][j] * inv[g][j];
                    ao[((size_t)b * NTOK + tok) * DIM + h * HD + n * 16 + col_l] = f2bf(val);
                }
            }
}

// ---------------- launcher ----------------

extern "C" void kernel_launch(void* const* d_in, const int* in_sizes, int n_in,
                              void* d_out, int out_size, void* d_ws, size_t ws_size,
                              hipStream_t stream)
{
    const float* x      = (const float*)d_in[0];
    const float* qkv_w  = (const float*)d_in[1];
    const float* q_bias = (const float*)d_in[2];
    const float* v_bias = (const float*)d_in[3];
    const float* rpb_t  = (const float*)d_in[4];
    const float* proj_w = (const float*)d_in[5];
    const float* proj_b = (const float*)d_in[6];
    const int*   relidx = (const int*)d_in[7];
    float* out = (float*)d_out;

    char* ws = (char*)d_ws;
    const size_t SZ_XBF  = (size_t)MROWS * DIM * 2;              // also reused as attn-out
    const size_t SZ_QKVW = (size_t)3 * DIM * DIM * 2;
    const size_t SZ_PRJW = (size_t)DIM * DIM * 2;
    const size_t SZ_QK   = (size_t)BATCH * NH * NTOK_P * HD * 2;
    const size_t SZ_VT   = (size_t)BATCH * NH * HD * MPAD * 2;

    unsigned short* x_bf = (unsigned short*)ws;
    unsigned short* ao   = x_bf; // aliased: x_bf dead after QKV gemm
    size_t off = SZ_XBF;
    unsigned short* qkvw_bf  = (unsigned short*)(ws + off); off += SZ_QKVW;
    unsigned short* projw_bf = (unsigned short*)(ws + off); off += SZ_PRJW;
    unsigned short* qbuf     = (unsigned short*)(ws + off); off += SZ_QK;
    unsigned short* kbuf     = (unsigned short*)(ws + off); off += SZ_QK;
    unsigned short* vtbuf    = (unsigned short*)(ws + off); off += SZ_VT;
    float* rpbf              = (float*)(ws + off);

    // prep (2 launches)
    const int NA4 = MROWS * DIM / 4, NB4 = 3 * DIM * DIM / 4, NC4 = DIM * DIM / 4;
    cvt3_bf16_kernel<<<(NA4 + NB4 + NC4 + 255) / 256, 256, 0, stream>>>(
        x, x_bf, NA4, qkv_w, qkvw_bf, NB4, proj_w, projw_bf, NC4);
    prep2_kernel<<<(NRPB + NPAD + 255) / 256, 256, 0, stream>>>(rpb_t, relidx, rpbf, vtbuf);

    // QKV gemm: R19 2-phase BK=64 counted-vmcnt (79.7 µs measured)
    qkv_gemm_kernel<<<99 * 18, 256, 0, stream>>>(x_bf, qkvw_bf, q_bias, v_bias,
                                                 qbuf, kbuf, vtbuf, MROWS, 18);
    // fused attention: one wave per 32 q-rows, split-KV-4
    attn_kernel<<<BATCH * NH * 7, 64, 0, stream>>>(qbuf, kbuf, vtbuf, rpbf, ao);
    // proj gemm: R22 ring-3 BK=32 (48KB -> 3 blocks/CU -> 594 blocks in one round)
    proj_gemm_kernel<<<99 * 6, 256, 0, stream>>>(ao, projw_bf, proj_b, out, MROWS, 6);
    (void)in_sizes; (void)n_in; (void)out_size; (void)ws_size;
}